// Round 14
// baseline (879.454 us; speedup 1.0000x reference)
//
#include <hip/hip_runtime.h>

#define NN 20000
#define NE 400000
#define NB_SCAN 20

typedef __attribute__((ext_vector_type(4))) float f32x4;
typedef _Float16 h2 __attribute__((ext_vector_type(2)));
typedef _Float16 h8 __attribute__((ext_vector_type(8)));

union H8 { h8 v; h2 p[4]; };

__device__ __forceinline__ float sigf(float x) { return 1.0f / (1.0f + __expf(-x)); }

__device__ __forceinline__ h8 rank1(_Float16 x, const h2 e[4]) {
    h2 xb = {x, x}; H8 f;
    #pragma unroll
    for (int j = 0; j < 4; ++j) f.p[j] = xb * e[j];
    return f.v;
}
__device__ __forceinline__ h8 rank3(_Float16 x0, _Float16 x1, _Float16 x2,
                                    const h2 e0[4], const h2 e1[4], const h2 e2[4]) {
    h2 x0b = {x0, x0}, x1b = {x1, x1}, x2b = {x2, x2}; H8 f;
    #pragma unroll
    for (int j = 0; j < 4; ++j) f.p[j] = x0b * e0[j] + x1b * e1[j] + x2b * e2[j];
    return f.v;
}
#define MFMA(a, b, c) __builtin_amdgcn_mfma_f32_16x16x32_f16(a, b, c, 0, 0, 0)

// ---------- weight prep: LDS-tiled transpose + fp16 + fold norms: dst[w][K] = sc*src[K][w] ----------
__global__ __launch_bounds__(256)
void prep_kernel(const float* __restrict__ s1, const float* __restrict__ s2,
                 int K1, int Kt, int Nw, float sc1, float sc2,
                 unsigned short* __restrict__ dst)
{
    __shared__ _Float16 tile[32][34];
    const int tx = threadIdx.x & 31, ty = threadIdx.x >> 5;
    const int K0 = blockIdx.x * 32, w0 = blockIdx.y * 32;
    #pragma unroll
    for (int r = 0; r < 4; ++r) {
        int K = K0 + ty + r * 8, w = w0 + tx;
        if (K < Kt && w < Nw) {
            float v = (K < K1) ? s1[(size_t)K * Nw + w] * sc1
                               : s2[(size_t)(K - K1) * Nw + w] * sc2;
            tile[ty + r * 8][tx] = (_Float16)v;
        }
    }
    __syncthreads();
    #pragma unroll
    for (int r = 0; r < 4; ++r) {
        int w = w0 + ty + r * 8, K = K0 + tx;
        if (w < Nw && K < Kt)
            dst[(size_t)w * Kt + K] = __builtin_bit_cast(unsigned short, tile[tx][ty + r * 8]);
    }
}

// ---------- counting sort of edges by destination row ----------
__global__ void hist_kernel(const int* __restrict__ eidx, int* __restrict__ counts)
{
    int e = blockIdx.x * 256 + threadIdx.x;
    if (e < NE) atomicAdd(&counts[eidx[e]], 1);
}

__global__ __launch_bounds__(1024)
void scan1_kernel(int* __restrict__ data, int* __restrict__ blksum)
{
    __shared__ int wsum[16];
    const int t = threadIdx.x, lane = t & 63, wv = t >> 6;
    const int idx = blockIdx.x * 1024 + t;
    int v = (idx < NN) ? data[idx] : 0;
    int s = v;
    #pragma unroll
    for (int d = 1; d < 64; d <<= 1) {
        int x = __shfl_up(s, d, 64);
        if (lane >= d) s += x;
    }
    if (lane == 63) wsum[wv] = s;
    __syncthreads();
    if (t < 16) {
        int ws = wsum[t];
        #pragma unroll
        for (int d = 1; d < 16; d <<= 1) {
            int x = __shfl_up(ws, d, 64);
            if (t >= d) ws += x;
        }
        wsum[t] = ws;
    }
    __syncthreads();
    if (idx < NN) data[idx] = (wv ? wsum[wv - 1] : 0) + s - v;
    if (t == 0) blksum[blockIdx.x] = wsum[15];
}

__global__ void scan2_kernel(int* __restrict__ blksum)
{
    if (threadIdx.x == 0) {
        int run = 0;
        for (int i = 0; i < NB_SCAN; ++i) { int x = blksum[i]; blksum[i] = run; run += x; }
    }
}

__global__ __launch_bounds__(1024)
void scan3_kernel(int* __restrict__ data, const int* __restrict__ blksum)
{
    int idx = blockIdx.x * 1024 + threadIdx.x;
    if (idx < NN) data[idx] += blksum[blockIdx.x];
}

__global__ void scatter_kernel(const int* __restrict__ eidx, int* __restrict__ cursor,
                               int* __restrict__ perm)
{
    int e = blockIdx.x * 256 + threadIdx.x;
    if (e < NE) {
        int r = eidx[e];
        int p = atomicAdd(&cursor[r], 1);
        perm[p] = e;
    }
}

// =============== message kernel: 64 sorted edges/block, LDS-chunked weights ===============
// wAB unified [128][768]: rows 0..95 = wA (hs weights), rows 96..127 = wB (hv weights)
__global__ __launch_bounds__(256, 3)
void msg_kernel(const float* __restrict__ nf, const float* __restrict__ ea,
                const int* __restrict__ eidx, const int* __restrict__ perm,
                const unsigned short* __restrict__ wAB,
                float* __restrict__ agg)
{
    const int e0 = blockIdx.x * 64;
    const int t = threadIdx.x;
    const int wid = t >> 6, lane = t & 63, ln = lane & 15, okt = lane >> 4;

    __shared__ __align__(16) _Float16 s_xsh[64][68];
    __shared__ __align__(16) _Float16 s_xv01[64][66];
    __shared__ __align__(16) _Float16 s_xv2[64][34];
    __shared__ __align__(16) _Float16 s_esh[64][8];
    __shared__ __align__(16) _Float16 s_evTh[64][3][8];
    __shared__ __align__(16) _Float16 lw[128][136];     // weight chunk (128 K-cols), 272B stride
    __shared__ int s_row[64], s_col[64], s_pe[64];

    _Float16 (*s_msg)[162] = (_Float16(*)[162])&lw[0][0];                  // overlay after GEMM
    _Float16 (*s_gate)[33] = (_Float16(*)[33])((char*)&lw[0][0] + 20736);

    if (t < 64) {
        int p = perm[e0 + t];
        s_pe[t] = p;
        s_row[t] = eidx[p];
        s_col[t] = eidx[NE + p];
    }
    __syncthreads();
    for (int i = t; i < 64 * 32; i += 256) {
        int e = i >> 5, c = i & 31;
        float v = ea[(size_t)s_pe[e] * 32 + c];
        if (c < 8) s_esh[e][c] = (_Float16)v;
        else { int d = c - 8; s_evTh[e][d % 3][d / 3] = (_Float16)v; }
    }
    for (int i = t; i < 64 * 40; i += 256) {
        int e = i / 40, q = i - e * 40;
        f32x4 f4 = *((const f32x4*)nf + (size_t)s_col[e] * 40 + q);
        if (q < 16) {
            #pragma unroll
            for (int j = 0; j < 4; ++j) s_xsh[e][q * 4 + j] = (_Float16)f4[j];
        } else {
            #pragma unroll
            for (int j = 0; j < 4; ++j) {
                int d = (q - 16) * 4 + j, u = d / 3, k = d - u * 3;
                if (k < 2) s_xv01[e][u * 2 + k] = (_Float16)f4[j];
                else       s_xv2[e][u] = (_Float16)f4[j];
            }
        }
    }

    f32x4 acc[12] = {};

    for (int ch = 0; ch < 6; ++ch) {
        __syncthreads();   // prev chunk's reads done (first iter: prologue staged)
        // ---- stage weight chunk: 128 rows x 16 slots of 16B (8 fp16) = 2048 jobs ----
        #pragma unroll
        for (int r = 0; r < 8; ++r) {
            int j = t + r * 256;
            int row = j >> 4, sl = j & 15;
            f32x4 v = *(const f32x4*)(wAB + (size_t)row * 768 + ch * 128 + sl * 8);
            *(f32x4*)&lw[row][sl * 8] = v;
        }
        __syncthreads();
        // ---- GEMM from LDS weights ----
        if (wid < 2) {
            // A: hs[64 x 96]; wave = N-tiles wid*3.., all 4 M-tiles
            #pragma unroll
            for (int ks = 0; ks < 4; ++ks) {
                const int ksg = ch * 4 + ks;
                const int co = ks * 32 + okt * 8;
                h8 b0 = *(const h8*)&lw[wid * 48 + ln][co];
                h8 b1 = *(const h8*)&lw[wid * 48 + 16 + ln][co];
                h8 b2 = *(const h8*)&lw[wid * 48 + 32 + ln][co];
                #pragma unroll
                for (int m = 0; m < 4; ++m) {
                    const int e = m * 16 + ln;
                    h8 a;
                    if (ch < 4) {                     // ss: xs[u]*es[v]
                        a = rank1(s_xsh[e][ksg * 4 + okt], (const h2*)s_esh[e]);
                    } else {                          // dd: sum_k xv[u][k]*ev[v][k]
                        const int u = (ksg - 16) * 4 + okt;
                        h2 x01 = *(const h2*)&s_xv01[e][u * 2];
                        a = rank3(x01[0], x01[1], s_xv2[e][u],
                                  (const h2*)s_evTh[e][0], (const h2*)s_evTh[e][1],
                                  (const h2*)s_evTh[e][2]);
                    }
                    acc[m * 3 + 0] = MFMA(a, b0, acc[m * 3 + 0]);
                    acc[m * 3 + 1] = MFMA(a, b1, acc[m * 3 + 1]);
                    acc[m * 3 + 2] = MFMA(a, b2, acc[m * 3 + 2]);
                }
            }
        } else {
            // B: hv[(k,e)=192 x 32]; wave = 6 M-tiles, both N-tiles
            const int MB = (wid - 2) * 6;
            #pragma unroll
            for (int ks = 0; ks < 4; ++ks) {
                const int ksg = ch * 4 + ks;
                const int co = ks * 32 + okt * 8;
                h8 b0 = *(const h8*)&lw[96 + ln][co];
                h8 b1 = *(const h8*)&lw[112 + ln][co];
                #pragma unroll
                for (int m = 0; m < 6; ++m) {
                    const int mt = MB + m, k = mt >> 2, e = ((mt & 3) << 4) + ln;
                    h8 a;
                    if (ch < 4) {                     // sv: xs[u]*ev[v][k]
                        a = rank1(s_xsh[e][ksg * 4 + okt], (const h2*)s_evTh[e][k]);
                    } else {                          // vs: xv[u][k]*es[v]
                        const int u = (ksg - 16) * 4 + okt;
                        _Float16 x = (k < 2) ? s_xv01[e][u * 2 + k] : s_xv2[e][u];
                        a = rank1(x, (const h2*)s_esh[e]);
                    }
                    acc[m * 2]     = MFMA(a, b0, acc[m * 2]);
                    acc[m * 2 + 1] = MFMA(a, b1, acc[m * 2 + 1]);
                }
            }
        }
    }
    __syncthreads();   // weights dead -> s_msg/s_gate may overwrite

    // ---- epilogue phase 1: scalars + gates ----
    if (wid < 2) {
        #pragma unroll
        for (int m = 0; m < 4; ++m)
            #pragma unroll
            for (int j = 0; j < 3; ++j)
                #pragma unroll
                for (int r = 0; r < 4; ++r) {
                    int e = m * 16 + okt * 4 + r;
                    int w = wid * 48 + j * 16 + ln;
                    float h = acc[m * 3 + j][r];
                    if (w < 64) s_msg[e][w] = (_Float16)(h * sigf(h));
                    else        s_gate[e][w - 64] = (_Float16)sigf(h);
                }
    }
    __syncthreads();
    // ---- epilogue phase 2: gated vectors ----
    if (wid >= 2) {
        const int mb = (wid - 2) * 6;
        #pragma unroll
        for (int m = 0; m < 6; ++m) {
            int mm = mb + m, k = mm >> 2;
            #pragma unroll
            for (int tt = 0; tt < 2; ++tt)
                #pragma unroll
                for (int r = 0; r < 4; ++r) {
                    int e = ((mm & 3) << 4) + okt * 4 + r;
                    int w2 = tt * 16 + ln;
                    s_msg[e][64 + w2 * 3 + k] =
                        (_Float16)(acc[m * 2 + tt][r] * (float)s_gate[e][w2]);
                }
        }
    }
    __syncthreads();

    // ---- segmented reduce over sorted rows ----
    if (t < 160) {
        int cur = s_row[0];
        float a = (float)s_msg[0][t];
        for (int e = 1; e < 64; ++e) {
            int r = s_row[e];
            float v = (float)s_msg[e][t];
            if (r != cur) {
                atomicAdd(agg + (size_t)cur * 160 + t, a);
                cur = r; a = v;
            } else a += v;
        }
        atomicAdd(agg + (size_t)cur * 160 + t, a);
    }
}

// =============== update kernel: 32 nodes/block, LDS-chunked weights, fused agglin ===============
__global__ __launch_bounds__(256, 3)
void upd_kernel(const float* __restrict__ nf, const float* __restrict__ agg,
                const unsigned short* __restrict__ wA,   // [96][7168] fp16
                const unsigned short* __restrict__ wB,   // [32][5120] fp16
                const float* __restrict__ Wlms, const float* __restrict__ Wlmv,
                const float* __restrict__ Wls, const float* __restrict__ Wlv,
                float* __restrict__ out)
{
    const int n0 = blockIdx.x * 32;
    const int t = threadIdx.x;
    const int wid = t >> 6, lane = t & 63, ln = lane & 15, okt = lane >> 4;

    __shared__ __align__(16) _Float16 s_xsh[32][68];
    __shared__ __align__(16) _Float16 s_xv01[32][66];
    __shared__ __align__(16) _Float16 s_xv2[32][34];
    __shared__ __align__(16) _Float16 s_ash[32][104];
    __shared__ __align__(16) _Float16 s_avTh[32][3][40];
    __shared__ __align__(16) _Float16 lw[128][136];     // weight chunk

    _Float16 (*s_hs2)[104] = (_Float16(*)[104])&lw[0][0];                 // overlay after GEMM
    _Float16 (*s_hv2)[34]  = (_Float16(*)[34])((char*)&lw[0][0] + 6656);

    for (int i = t; i < 32 * 40; i += 256) {
        int n = i / 40, q = i - n * 40;
        f32x4 f4 = *((const f32x4*)nf + (size_t)(n0 + n) * 40 + q);
        if (q < 16) {
            #pragma unroll
            for (int j = 0; j < 4; ++j) s_xsh[n][q * 4 + j] = (_Float16)f4[j];
        } else {
            #pragma unroll
            for (int j = 0; j < 4; ++j) {
                int d = (q - 16) * 4 + j, u = d / 3, k = d - u * 3;
                if (k < 2) s_xv01[n][u * 2 + k] = (_Float16)f4[j];
                else       s_xv2[n][u] = (_Float16)f4[j];
            }
        }
    }
    // folded agglin (linear commuted past segment_sum), direct-global agg reads
    const float* agr = agg + (size_t)n0 * 160;
    #pragma unroll
    for (int r = 0; r < 12; ++r) {
        int o = t + r * 256;
        int n = o / 96, q = o - n * 96;
        float a = 0.f;
        #pragma unroll
        for (int u = 0; u < 64; ++u) a = fmaf(agr[n * 160 + u], Wlms[u * 96 + q], a);
        s_ash[n][q] = (_Float16)(a * 0.125f);
    }
    #pragma unroll
    for (int r = 0; r < 12; ++r) {
        int o = t + r * 256;
        int n = o / 96, q = o - n * 96, k = q >> 5, v = q & 31;
        float a = 0.f;
        #pragma unroll
        for (int u = 0; u < 32; ++u) a = fmaf(agr[n * 160 + 64 + u * 3 + k], Wlmv[u * 32 + v], a);
        s_avTh[n][k][v] = (_Float16)(a * 0.17677669529663687f);
    }

    f32x4 acc[6] = {};

    for (int ch = 0; ch < 56; ++ch) {
        __syncthreads();
        // ---- stage chunk: wA 96x16 slots = 1536 jobs (6/thread); wB 32x16 = 512 (2/thread) if ch<40 ----
        #pragma unroll
        for (int r = 0; r < 6; ++r) {
            int j = t + r * 256;
            int row = j >> 4, sl = j & 15;
            f32x4 v = *(const f32x4*)(wA + (size_t)row * 7168 + ch * 128 + sl * 8);
            *(f32x4*)&lw[row][sl * 8] = v;
        }
        if (ch < 40) {
            #pragma unroll
            for (int r = 0; r < 2; ++r) {
                int j = t + r * 256;
                int row = j >> 4, sl = j & 15;
                f32x4 v = *(const f32x4*)(wB + (size_t)row * 5120 + ch * 128 + sl * 8);
                *(f32x4*)&lw[96 + row][sl * 8] = v;
            }
        }
        __syncthreads();
        // ---- GEMM ----
        if (wid < 2) {
            // A: hs2[32 x 96]; N-tiles wid*3.., 2 M-tiles, K chunk = 4 steps of 32
            #pragma unroll
            for (int ks = 0; ks < 4; ++ks) {
                const int S = ch * 4 + ks;           // 32-K step id, 0..223
                const int co = ks * 32 + okt * 8;
                h8 b0 = *(const h8*)&lw[wid * 48 + ln][co];
                h8 b1 = *(const h8*)&lw[wid * 48 + 16 + ln][co];
                h8 b2 = *(const h8*)&lw[wid * 48 + 32 + ln][co];
                h8 a0, a1;
                if (ch < 48) {                        // ss: K = u*96 + p*32
                    const int u = S / 3, p = S - u * 3;
                    const int v0 = p * 32 + okt * 8;
                    a0 = rank1(s_xsh[ln][u],      (const h2*)&s_ash[ln][v0]);
                    a1 = rank1(s_xsh[16 + ln][u], (const h2*)&s_ash[16 + ln][v0]);
                } else {                              // vv: u = S-192
                    const int u = S - 192, v0 = okt * 8;
                    h2 xa = *(const h2*)&s_xv01[ln][u * 2];
                    h2 xb = *(const h2*)&s_xv01[16 + ln][u * 2];
                    a0 = rank3(xa[0], xa[1], s_xv2[ln][u],
                               (const h2*)&s_avTh[ln][0][v0], (const h2*)&s_avTh[ln][1][v0],
                               (const h2*)&s_avTh[ln][2][v0]);
                    a1 = rank3(xb[0], xb[1], s_xv2[16 + ln][u],
                               (const h2*)&s_avTh[16 + ln][0][v0], (const h2*)&s_avTh[16 + ln][1][v0],
                               (const h2*)&s_avTh[16 + ln][2][v0]);
                }
                acc[0] = MFMA(a0, b0, acc[0]); acc[1] = MFMA(a0, b1, acc[1]); acc[2] = MFMA(a0, b2, acc[2]);
                acc[3] = MFMA(a1, b0, acc[3]); acc[4] = MFMA(a1, b1, acc[4]); acc[5] = MFMA(a1, b2, acc[5]);
            }
        } else if (ch < 40) {
            // B: hv2[(k,n)=96 x 32]; 6 M-tiles, N-tile (wid-2)
            #pragma unroll
            for (int ks = 0; ks < 4; ++ks) {
                const int S = ch * 4 + ks;           // 0..159
                const int co = ks * 32 + okt * 8;
                h8 b = *(const h8*)&lw[96 + (wid - 2) * 16 + ln][co];
                if (S < 64) {                         // sv: u = S, v0 = okt*8
                    const int u = S, v0 = okt * 8;
                    #pragma unroll
                    for (int m = 0; m < 6; ++m) {
                        const int k = m >> 1, n = ((m & 1) << 4) + ln;
                        h8 a = rank1(s_xsh[n][u], (const h2*)&s_avTh[n][k][v0]);
                        acc[m] = MFMA(a, b, acc[m]);
                    }
                } else {                              // vs: Kp = u*96 + p*32
                    const int Sp = S - 64;
                    const int u = Sp / 3, p = Sp - u * 3;
                    const int v0 = p * 32 + okt * 8;
                    #pragma unroll
                    for (int m = 0; m < 6; ++m) {
                        const int k = m >> 1, n = ((m & 1) << 4) + ln;
                        _Float16 x = (k < 2) ? s_xv01[n][u * 2 + k] : s_xv2[n][u];
                        h8 a = rank1(x, (const h2*)&s_ash[n][v0]);
                        acc[m] = MFMA(a, b, acc[m]);
                    }
                }
            }
        }
    }
    __syncthreads();   // weights dead -> s_hs2/s_hv2 may overwrite

    // ---- store C tiles (fp16) ----
    if (wid < 2) {
        #pragma unroll
        for (int m = 0; m < 2; ++m)
            #pragma unroll
            for (int j = 0; j < 3; ++j)
                #pragma unroll
                for (int r = 0; r < 4; ++r)
                    s_hs2[m * 16 + okt * 4 + r][wid * 48 + j * 16 + ln] = (_Float16)acc[m * 3 + j][r];
    } else {
        #pragma unroll
        for (int m = 0; m < 6; ++m)
            #pragma unroll
            for (int r = 0; r < 4; ++r)
                s_hv2[m * 16 + okt * 4 + r][(wid - 2) * 16 + ln] = (_Float16)acc[m][r];
    }
    __syncthreads();
    for (int i = t; i < 32 * 96; i += 256) {
        int n = i / 96, w = i - n * 96;
        float h = (float)s_hs2[n][w];
        s_hs2[n][w] = (_Float16)((w < 64) ? h * sigf(h) : sigf(h));
    }
    __syncthreads();
    for (int i = t; i < 96 * 32; i += 256) {
        int R = i >> 5, w2 = i & 31, n = R & 31;
        s_hv2[R][w2] = (_Float16)((float)s_hv2[R][w2] * (float)s_hs2[n][64 + w2]);
    }
    __syncthreads();
    for (int i = t; i < 32 * 64; i += 256) {
        int n = i >> 6, w = i & 63;
        float a = 0.f;
        #pragma unroll
        for (int u = 0; u < 64; ++u) a = fmaf((float)s_hs2[n][u], Wls[u * 64 + w], a);
        size_t o = (size_t)(n0 + n) * 160 + w;
        out[o] = nf[o] + a * 0.125f;
    }
    for (int i = t; i < 32 * 96; i += 256) {
        int n = i / 96, wk = i - n * 96, w = wk / 3, k = wk - w * 3;
        float a = 0.f;
        #pragma unroll
        for (int u = 0; u < 32; ++u) a = fmaf((float)s_hv2[k * 32 + n][u], Wlv[u * 32 + w], a);
        size_t o = (size_t)(n0 + n) * 160 + 64 + wk;
        out[o] = nf[o] + a * 0.17677669529663687f;
    }
}

extern "C" void kernel_launch(void* const* d_in, const int* in_sizes, int n_in,
                              void* d_out, int out_size, void* d_ws, size_t ws_size,
                              hipStream_t stream) {
    const float* nf   = (const float*)d_in[0];
    const float* ea   = (const float*)d_in[1];
    const int*   eidx = (const int*)d_in[3];
    const float* Wmss = (const float*)d_in[4];
    const float* Wmvv = (const float*)d_in[5];
    const float* Wmsv = (const float*)d_in[6];
    const float* Wmvs = (const float*)d_in[7];
    const float* Wlms = (const float*)d_in[8];
    const float* Wlmv = (const float*)d_in[9];
    const float* Wuss = (const float*)d_in[10];
    const float* Wuvv = (const float*)d_in[11];
    const float* Wusv = (const float*)d_in[12];
    const float* Wuvs = (const float*)d_in[13];
    const float* Wlus = (const float*)d_in[14];
    const float* Wluv = (const float*)d_in[15];
    float* out = (float*)d_out;

    float* agg = (float*)d_ws;                          // [NN,160]
    unsigned short* wAm = (unsigned short*)(agg + (size_t)NN * 160);  // [96][768]
    unsigned short* wBm = wAm + 96 * 768;                             // [32][768] (contiguous)
    unsigned short* wAu = wBm + 32 * 768;                             // [96][7168]
    unsigned short* wBu = wAu + (size_t)96 * 7168;                    // [32][5120]
    int* counts = (int*)(wBu + (size_t)32 * 5120);      // [NN] -> becomes cursor
    int* perm   = counts + NN;                          // [NE]
    int* blksum = perm + NE;                            // [NB_SCAN] (+pad)

    const float NSM = 0.03608439182435161f;   // 1/sqrt(768)
    const float NSU = 0.011811365506297619f;  // 1/sqrt(7168)
    const float NVU = 0.013975424859373686f;  // 1/sqrt(5120)
    const float S3  = 0.57735026918962576f;   // 1/sqrt(3)

    hipMemsetAsync(agg, 0, (size_t)NN * 160 * sizeof(float), stream);
    hipMemsetAsync(counts, 0, (size_t)NN * sizeof(int), stream);

    prep_kernel<<<dim3(24, 3), 256, 0, stream>>>(Wmss, Wmvv, 512, 768, 96, NSM, NSM * S3, wAm);
    prep_kernel<<<dim3(24, 1), 256, 0, stream>>>(Wmsv, Wmvs, 512, 768, 32, NSM, NSM, wBm);
    prep_kernel<<<dim3(224, 3), 256, 0, stream>>>(Wuss, Wuvv, 6144, 7168, 96, NSU, NSU * S3, wAu);
    prep_kernel<<<dim3(160, 1), 256, 0, stream>>>(Wusv, Wuvs, 2048, 5120, 32, NVU, NVU, wBu);

    hist_kernel<<<(NE + 255) / 256, 256, 0, stream>>>(eidx, counts);
    scan1_kernel<<<NB_SCAN, 1024, 0, stream>>>(counts, blksum);
    scan2_kernel<<<1, 64, 0, stream>>>(blksum);
    scan3_kernel<<<NB_SCAN, 1024, 0, stream>>>(counts, blksum);
    scatter_kernel<<<(NE + 255) / 256, 256, 0, stream>>>(eidx, counts, perm);

    msg_kernel<<<NE / 64, 256, 0, stream>>>(nf, ea, eidx, perm, wAm, agg);
    upd_kernel<<<NN / 32, 256, 0, stream>>>(nf, agg, wAu, wBu, Wlms, Wlmv, Wlus, Wluv, out);
}